// Round 2
// baseline (573.244 us; speedup 1.0000x reference)
//
#include <hip/hip_runtime.h>

// GwcVolume: group-wise correlation cost volume. FP32 in / FP32 out.
// B=1, F=320, G=40 groups, C=8 ch/group, H=128, W=256, D=48 disparities.
// lr[g,d,h,w] = (w>=d) ? mean_c L[g,c,h,w]*R[g,c,h,w-d] : 0
// rl[g,d,h,w] = (w < W-d) ? lr[g,d,h,w+d] : 0   (pure left-rotation of lr row;
//   the masked lr head lands exactly on rl's should-be-zero tail).
//
// Dtype evidence (round 1): writing data produced absmax=NaN. Finite bf16
// inputs cannot produce NaN through this kernel; fp32 buffers misread as
// bf16 DO yield NaN bit-patterns (low mantissa halves). => inputs are fp32,
// hence reference (and d_out) are fp32.

#define G_   40
#define CPG  8
#define H_   128
#define W_   256
#define HW_  (H_ * W_)

__global__ __launch_bounds__(256, 4)
void gwc_volume_kernel(const float* __restrict__ Lp,
                       const float* __restrict__ Rp,
                       const int* __restrict__ bins,
                       float* __restrict__ out,
                       int D)
{
    __shared__ float Rlds[4 * CPG * W_];   // 32 KB: per-wave right row
    __shared__ int   bins_s[64];

    const int tid = threadIdx.x;
    const int wv  = tid >> 6;        // wave 0..3
    const int ln  = tid & 63;        // lane 0..63
    const int w4  = ln << 2;         // this lane's 4 w positions: w4..w4+3

    const int row = blockIdx.x * 4 + wv;   // 0..5119
    const int g   = row >> 7;              // / H_
    const int h   = row & (H_ - 1);

    if (tid < D) bins_s[tid] = bins[tid];

    const size_t in_row = (size_t)(g * CPG) * HW_ + (size_t)h * W_;

    // Left row -> registers (pre-scaled by 1/C); right row -> LDS.
    float4 lf[CPG];
    float* Rw = &Rlds[wv * CPG * W_];
    #pragma unroll
    for (int c = 0; c < CPG; ++c) {
        float4 lv = *(const float4*)(Lp + in_row + (size_t)c * HW_ + w4);
        float4 rv = *(const float4*)(Rp + in_row + (size_t)c * HW_ + w4);
        lf[c] = make_float4(lv.x * 0.125f, lv.y * 0.125f,
                            lv.z * 0.125f, lv.w * 0.125f);
        *(float4*)(&Rw[c * W_ + w4]) = rv;
    }
    __syncthreads();

    float* out_lr = out;
    float* out_rl = out + (size_t)G_ * D * HW_;
    const size_t obase = (size_t)g * D * HW_ + (size_t)h * W_;

    // Disparity batches of 4. Window for (c, batch): R[w4-d0-4 .. w4-d0+3],
    // two aligned float4 LDS reads (w4 and d0 both ≡ 0 mod 4; clamped
    // entries are only consumed where the w>=d mask zeroes the result).
    #pragma unroll 1
    for (int di0 = 0; di0 < D; di0 += 4) {
        const int d0   = bins_s[di0];
        const int base = w4 - d0;
        const int ihi  = (base     < 0) ? 0 : base;
        const int ilo  = (base - 4 < 0) ? 0 : base - 4;

        float4 a0 = make_float4(0.f, 0.f, 0.f, 0.f);
        float4 a1 = a0, a2 = a0, a3 = a0;

        #pragma unroll
        for (int c = 0; c < CPG; ++c) {
            const float* rr  = &Rw[c * W_];
            float4 rlo = *(const float4*)(rr + ilo);
            float4 rhi = *(const float4*)(rr + ihi);
            float4 lc  = lf[c];
            // d = d0+0 : R indices w4+j-d0 -> rhi.xyzw
            a0.x = fmaf(lc.x, rhi.x, a0.x); a0.y = fmaf(lc.y, rhi.y, a0.y);
            a0.z = fmaf(lc.z, rhi.z, a0.z); a0.w = fmaf(lc.w, rhi.w, a0.w);
            // d = d0+1
            a1.x = fmaf(lc.x, rlo.w, a1.x); a1.y = fmaf(lc.y, rhi.x, a1.y);
            a1.z = fmaf(lc.z, rhi.y, a1.z); a1.w = fmaf(lc.w, rhi.z, a1.w);
            // d = d0+2
            a2.x = fmaf(lc.x, rlo.z, a2.x); a2.y = fmaf(lc.y, rlo.w, a2.y);
            a2.z = fmaf(lc.z, rhi.x, a2.z); a2.w = fmaf(lc.w, rhi.y, a2.w);
            // d = d0+3
            a3.x = fmaf(lc.x, rlo.y, a3.x); a3.y = fmaf(lc.y, rlo.z, a3.y);
            a3.z = fmaf(lc.z, rlo.w, a3.z); a3.w = fmaf(lc.w, rhi.x, a3.w);
        }

        float4 av[4] = {a0, a1, a2, a3};
        #pragma unroll
        for (int dd = 0; dd < 4; ++dd) {
            float4 a   = av[dd];
            const int di = di0 + dd;
            const int d  = d0 + dd;
            float4 v;
            v.x = (w4 + 0 >= d) ? a.x : 0.f;
            v.y = (w4 + 1 >= d) ? a.y : 0.f;
            v.z = (w4 + 2 >= d) ? a.z : 0.f;
            v.w = (w4 + 3 >= d) ? a.w : 0.f;

            const size_t o = obase + (size_t)di * HW_;
            *(float4*)(out_lr + o + w4) = v;             // lr: aligned 16B

            // rl row = lr row rotated left by d (masked head -> zero tail).
            float* ro = out_rl + o;
            ro[(w4 + 0 - d) & (W_ - 1)] = v.x;
            ro[(w4 + 1 - d) & (W_ - 1)] = v.y;
            ro[(w4 + 2 - d) & (W_ - 1)] = v.z;
            ro[(w4 + 3 - d) & (W_ - 1)] = v.w;
        }
    }
}

extern "C" void kernel_launch(void* const* d_in, const int* in_sizes, int n_in,
                              void* d_out, int out_size, void* d_ws, size_t ws_size,
                              hipStream_t stream) {
    const float* L  = (const float*)d_in[0];
    const float* R  = (const float*)d_in[1];
    const int* bins = (const int*)d_in[2];
    float* out      = (float*)d_out;
    const int D = in_sizes[2];                 // 48
    const int blocks = (G_ * H_) / 4;          // 1280 blocks x 256 threads
    gwc_volume_kernel<<<blocks, 256, 0, stream>>>(L, R, bins, out, D);
}